// Round 11
// baseline (92437.665 us; speedup 1.0000x reference)
//
#include <hip/hip_runtime.h>
#include <math.h>

// LSTM T=32768, B=1, I=128, H=512. Persistent kernel: 32 WGs x 512 threads.
// R11 = R9 (tag-in-band 8B packets at MALL, wave0 polls-then-computes,
// parity-double-buffered LDS, each wave owns 2 h elements end-to-end,
// atomic-free out[], 256-VGPR budget) + 2-deep PIPELINED poll: two
// generations of 4x8B loads kept in flight, halving the sampling cadence.
// This cuts both mean detect latency and the max-over-32-WGs phase term.

#define T_SEQ 32768
#define HID   512
#define INP   128
#define NWG   32
#define NTH   512   // 8 waves; wave0 polls then computes
#define HSL   16    // h elements per WG
#define KW    64    // W_hh weights per thread
#define KX    16    // W_ih weights per thread
#define NPK   256   // packets per parity (2 h each)

typedef unsigned long long u64;
typedef unsigned int u32;

__device__ __forceinline__ float fast_sigmoid(float x) {
    return 1.0f / (1.0f + __expf(-x));
}
__device__ __forceinline__ float fast_tanh(float x) {
    float a = fabsf(x);
    float e = __expf(-2.0f * a);          // underflows to 0 for large a -> r=1
    float r = (1.0f - e) / (1.0f + e);
    return copysignf(r, x);
}

__global__ void __launch_bounds__(NTH, 1) lstm_persist(
    const float* __restrict__ x,
    const float* __restrict__ W_ih,
    const float* __restrict__ W_hh,
    const float* __restrict__ b_ih,
    const float* __restrict__ b_hh,
    const float* __restrict__ W1,
    const float* __restrict__ b1,
    const float* __restrict__ Wout,
    u64* __restrict__ hbuf,             // 2 x 256 packets, pre-zeroed
    float* __restrict__ out)
{
    const int w   = blockIdx.x;
    const int tid = threadIdx.x;
    const int wv  = tid >> 6;           // 0..7
    const int l   = tid & 63;
    const int rw  = l >> 3;             // 0..7 = (gate g, elem b)
    const int j   = l & 7;              // K-chunk
    const int g   = rw >> 1;
    const int b   = rw & 1;
    const bool is_out = (w == 0 && wv == 1);   // WG0 wave1 computes out[]

    __shared__ __align__(16) float h_lds[2][HID];   // parity double buffer

    // each wave owns elements {16w + 2wv, 16w + 2wv + 1}; 8 rows (4 gates x 2)
    const int grow = g * HID + w * HSL + 2 * wv + b;

    // ---- weights, j-rotated order to match the LDS read schedule ----
    float wr[KW], wi[KX];
#pragma unroll
    for (int kk = 0; kk < 16; ++kk) {
        const int p = (kk + 2 * j) & 15;
        const float4 v4 = *(const float4*)&W_hh[grow * HID + j * KW + 4 * p];
        wr[4 * kk + 0] = v4.x; wr[4 * kk + 1] = v4.y;
        wr[4 * kk + 2] = v4.z; wr[4 * kk + 3] = v4.w;
    }
#pragma unroll
    for (int k = 0; k < KX; k += 4) {
        const float4 v4 = *(const float4*)&W_ih[grow * INP + j * KX + k];
        wi[k] = v4.x; wi[k + 1] = v4.y; wi[k + 2] = v4.z; wi[k + 3] = v4.w;
    }
    float brow = b_ih[grow] + b_hh[grow];

    // out-projection weights (WG0 wave1): lane l covers h indices l + 64*i
    float weff_o[8];
    float be = 0.0f;
#pragma unroll
    for (int i = 0; i < 8; ++i) weff_o[i] = 0.0f;
    if (is_out) {
#pragma unroll
        for (int i = 0; i < 8; ++i) {
            float s = 0.0f;
            for (int p = 0; p < 25; ++p) s += Wout[p] * W1[p * HID + l + 64 * i];
            weff_o[i] = s;
        }
        for (int p = 0; p < 25; ++p) be += b1[p] * Wout[p];
    }
    // pin against in-loop memory clobbers
#pragma unroll
    for (int k = 0; k < KW; ++k) asm volatile("" : "+v"(wr[k]));
#pragma unroll
    for (int k = 0; k < KX; ++k) asm volatile("" : "+v"(wi[k]));
#pragma unroll
    for (int i = 0; i < 8; ++i) asm volatile("" : "+v"(weff_o[i]));
    asm volatile("" : "+v"(brow));
    asm volatile("" : "+v"(be));

    float c = 0.0f;
    float xa[KX];
#pragma unroll
    for (int k = 0; k < KX; ++k) xa[k] = x[j * KX + k];

    bool dead = false;   // safety latch: never hang the device

    for (u32 t = 0; t <= T_SEQ; ++t) {
        if (t == T_SEQ && w != 0) break;   // only WG0 runs the tail iteration

        // ---- x-dot partials for step t (pure VALU; overlaps the poll) ----
        float xd0 = 0.0f, xd1 = 0.0f, xd2 = 0.0f, xd3 = 0.0f;
#pragma unroll
        for (int k = 0; k < KX; k += 4) {
            xd0 += wi[k + 0] * xa[k + 0];
            xd1 += wi[k + 1] * xa[k + 1];
            xd2 += wi[k + 2] * xa[k + 2];
            xd3 += wi[k + 3] * xa[k + 3];
        }
        // xa consumed -> prefetch x_{t+1}. Compute waves: before the barrier
        // (latency hides inside the wait). Poller: after the barrier.
        const int tn = (t + 1 < T_SEQ) ? (int)(t + 1) : (T_SEQ - 1);
        if (wv != 0) {
#pragma unroll
            for (int k = 0; k < KX; k += 4) {
                const float4 x4 = *(const float4*)&x[tn * INP + j * KX + k];
                xa[k + 0] = x4.x; xa[k + 1] = x4.y;
                xa[k + 2] = x4.z; xa[k + 3] = x4.w;
            }
        }

        // ---- wave0: 2-deep pipelined poll of the 256 packets ----
        // Two independent generations (A,B) of 4x8B loads stay in flight;
        // while checking one, the other is already travelling. Sampling
        // cadence ~RTT/2 instead of RTT.
        if (wv == 0 && !dead) {
            const u64* P = hbuf + (t & 1) * NPK;
            float2* HL = (float2*)h_lds[t & 1];
            u64 A[4], B[4];
            bool mine = false;
            int guard = 0;
#pragma unroll
            for (int i = 0; i < 4; ++i)
                A[i] = __hip_atomic_load(&P[l + 64 * i], __ATOMIC_RELAXED,
                                         __HIP_MEMORY_SCOPE_AGENT);
#pragma unroll
            for (int i = 0; i < 4; ++i)
                B[i] = __hip_atomic_load(&P[l + 64 * i], __ATOMIC_RELAXED,
                                         __HIP_MEMORY_SCOPE_AGENT);
            while (true) {
                // ---- generation A: check (waits only for A), else reissue --
                if (!mine) {
                    bool ok = true;
#pragma unroll
                    for (int i = 0; i < 4; ++i)
                        ok = ok && ((((u32)A[i]) ^ t) & 15u) == 0u;
                    if (ok) {
#pragma unroll
                        for (int i = 0; i < 4; ++i) {
                            float2 hp;
                            hp.x = __uint_as_float((u32)A[i]);
                            hp.y = __uint_as_float((u32)(A[i] >> 32));
                            HL[l + 64 * i] = hp;
                        }
                        mine = true;
                    } else {
#pragma unroll
                        for (int i = 0; i < 4; ++i)
                            A[i] = __hip_atomic_load(&P[l + 64 * i],
                                                     __ATOMIC_RELAXED,
                                                     __HIP_MEMORY_SCOPE_AGENT);
                    }
                }
                if (__ballot(mine) == ~0ull) break;
                // ---- generation B ----
                if (!mine) {
                    bool ok = true;
#pragma unroll
                    for (int i = 0; i < 4; ++i)
                        ok = ok && ((((u32)B[i]) ^ t) & 15u) == 0u;
                    if (ok) {
#pragma unroll
                        for (int i = 0; i < 4; ++i) {
                            float2 hp;
                            hp.x = __uint_as_float((u32)B[i]);
                            hp.y = __uint_as_float((u32)(B[i] >> 32));
                            HL[l + 64 * i] = hp;
                        }
                        mine = true;
                    } else {
#pragma unroll
                        for (int i = 0; i < 4; ++i)
                            B[i] = __hip_atomic_load(&P[l + 64 * i],
                                                     __ATOMIC_RELAXED,
                                                     __HIP_MEMORY_SCOPE_AGENT);
                    }
                }
                if (__ballot(mine) == ~0ull) break;
                if (++guard > (1 << 21)) { dead = true; break; }  // no hang
            }
        }
        __syncthreads();

        float hv = 0.0f;
        if (t < T_SEQ) {
            float a0 = xd0, a1 = xd1, a2 = xd2, a3 = xd3;
            const float4* hl4 = (const float4*)&h_lds[t & 1][j * KW];
#pragma unroll
            for (int kk = 0; kk < 16; ++kk) {
                const int p = (kk + 2 * j) & 15;
                const float4 h4 = hl4[p];
                a0 += wr[4 * kk + 0] * h4.x;
                a1 += wr[4 * kk + 1] * h4.y;
                a2 += wr[4 * kk + 2] * h4.z;
                a3 += wr[4 * kk + 3] * h4.w;
            }
            // poller's x-prefetch (after barrier, overlaps the h-dot)
            if (wv == 0) {
#pragma unroll
                for (int k = 0; k < KX; k += 4) {
                    const float4 x4 = *(const float4*)&x[tn * INP + j * KX + k];
                    xa[k + 0] = x4.x; xa[k + 1] = x4.y;
                    xa[k + 2] = x4.z; xa[k + 3] = x4.w;
                }
            }
            // xor-butterfly over j: every lane holds its row's full sum
            float acc = (a0 + a1) + (a2 + a3);
            acc += __shfl_xor(acc, 1);
            acc += __shfl_xor(acc, 2);
            acc += __shfl_xor(acc, 4);
            acc += brow;
            // gates of element b live at rw = b, b+2, b+4, b+6 (valid l<16)
            const float ig = acc;
            const float fg = __shfl(acc, l + 16);
            const float gg = __shfl(acc, l + 32);
            const float og = __shfl(acc, l + 48);
            const float iv = fast_sigmoid(ig);
            const float fv = fast_sigmoid(fg);
            const float gv = fast_tanh(gg);
            const float ov = fast_sigmoid(og);
            c = fv * c + iv * gv;
            hv = ov * fast_tanh(c);
            // pack (h_even tagged in low nibble, h_odd full) and publish:
            // one 8B store from lane 0 of each wave
            const float hv1 = __shfl(hv, 8);     // element b=1 (lane 8)
            if (l == 0) {
                const u32 b0 = (__float_as_uint(hv) & ~15u) | ((t + 1) & 15u);
                const u32 b1v = __float_as_uint(hv1);
                const u64 pkt = ((u64)b1v << 32) | (u64)b0;
                __hip_atomic_store(&hbuf[((t + 1) & 1) * NPK + w * 8 + wv], pkt,
                                   __ATOMIC_RELAXED, __HIP_MEMORY_SCOPE_AGENT);
            }
        }

        // out[t-1] = dot(h_{t-1}, w_eff) + b_eff — WG0 wave1, after publish
        if (is_out && t >= 1) {
            float pd = 0.0f;
#pragma unroll
            for (int i = 0; i < 8; ++i)
                pd += h_lds[t & 1][l + 64 * i] * weff_o[i];
            pd += __shfl_xor(pd, 1);
            pd += __shfl_xor(pd, 2);
            pd += __shfl_xor(pd, 4);
            pd += __shfl_xor(pd, 8);
            pd += __shfl_xor(pd, 16);
            pd += __shfl_xor(pd, 32);
            if (l == 0) out[t - 1] = pd + be;
        }
    }
}

extern "C" void kernel_launch(void* const* d_in, const int* in_sizes, int n_in,
                              void* d_out, int out_size, void* d_ws, size_t ws_size,
                              hipStream_t stream)
{
    const float* x    = (const float*)d_in[0];
    const float* W_ih = (const float*)d_in[1];
    const float* W_hh = (const float*)d_in[2];
    const float* b_ih = (const float*)d_in[3];
    const float* b_hh = (const float*)d_in[4];
    const float* W1   = (const float*)d_in[5];
    const float* b1   = (const float*)d_in[6];
    const float* Wout = (const float*)d_in[7];
    float* out = (float*)d_out;

    u64* hbuf = (u64*)d_ws;    // 2 x 256 packets = 4 KB

    // zero packets: tag nibble 0 + h 0 == valid initial state for step 0
    hipMemsetAsync(d_ws, 0, 2 * NPK * sizeof(u64), stream);
    lstm_persist<<<NWG, NTH, 0, stream>>>(x, W_ih, W_hh, b_ih, b_hh, W1, b1,
                                          Wout, hbuf, out);
}

// Round 12
// 65559.082 us; speedup vs baseline: 1.4100x; 1.4100x over previous
//
#include <hip/hip_runtime.h>
#include <math.h>

// LSTM T=32768, B=1, I=128, H=512. Persistent kernel: 32 WGs x 512 threads.
// R12 = R9 (tag-in-band 8B packets at MALL, wave0 polls-then-computes,
// parity-double-buffered LDS, each wave owns 2 h elements end-to-end,
// atomic-free out[], 256-VGPR budget, single-generation poll) + COALESCED
// PUBLISH: waves stage their 8B packets in LDS; after one extra barrier,
// wave0 lanes 0-7 store the WG's whole 64B line with ONE coalesced
// global_store_dwordx2 instruction (8 contiguous atomic 8B stores -> one
// fabric transaction) instead of 8 scattered per-wave stores spread over
// the activation skew. Wire format and consumer unchanged.

#define T_SEQ 32768
#define HID   512
#define INP   128
#define NWG   32
#define NTH   512   // 8 waves; wave0 polls then computes
#define HSL   16    // h elements per WG
#define KW    64    // W_hh weights per thread
#define KX    16    // W_ih weights per thread
#define NPK   256   // packets per parity (2 h each)

typedef unsigned long long u64;
typedef unsigned int u32;

__device__ __forceinline__ float fast_sigmoid(float x) {
    return 1.0f / (1.0f + __expf(-x));
}
__device__ __forceinline__ float fast_tanh(float x) {
    float a = fabsf(x);
    float e = __expf(-2.0f * a);          // underflows to 0 for large a -> r=1
    float r = (1.0f - e) / (1.0f + e);
    return copysignf(r, x);
}

__global__ void __launch_bounds__(NTH, 1) lstm_persist(
    const float* __restrict__ x,
    const float* __restrict__ W_ih,
    const float* __restrict__ W_hh,
    const float* __restrict__ b_ih,
    const float* __restrict__ b_hh,
    const float* __restrict__ W1,
    const float* __restrict__ b1,
    const float* __restrict__ Wout,
    u64* __restrict__ hbuf,             // 2 x 256 packets, pre-zeroed
    float* __restrict__ out)
{
    const int w   = blockIdx.x;
    const int tid = threadIdx.x;
    const int wv  = tid >> 6;           // 0..7
    const int l   = tid & 63;
    const int rw  = l >> 3;             // 0..7 = (gate g, elem b)
    const int j   = l & 7;              // K-chunk
    const int g   = rw >> 1;
    const int b   = rw & 1;
    const bool is_out = (w == 0 && wv == 1);   // WG0 wave1 computes out[]

    __shared__ __align__(16) float h_lds[2][HID];   // parity double buffer
    __shared__ u64 gather_lds[8];                   // per-wave packet staging

    // each wave owns elements {16w + 2wv, 16w + 2wv + 1}; 8 rows (4 gates x 2)
    const int grow = g * HID + w * HSL + 2 * wv + b;

    // ---- weights, j-rotated order to match the LDS read schedule ----
    float wr[KW], wi[KX];
#pragma unroll
    for (int kk = 0; kk < 16; ++kk) {
        const int p = (kk + 2 * j) & 15;
        const float4 v4 = *(const float4*)&W_hh[grow * HID + j * KW + 4 * p];
        wr[4 * kk + 0] = v4.x; wr[4 * kk + 1] = v4.y;
        wr[4 * kk + 2] = v4.z; wr[4 * kk + 3] = v4.w;
    }
#pragma unroll
    for (int k = 0; k < KX; k += 4) {
        const float4 v4 = *(const float4*)&W_ih[grow * INP + j * KX + k];
        wi[k] = v4.x; wi[k + 1] = v4.y; wi[k + 2] = v4.z; wi[k + 3] = v4.w;
    }
    float brow = b_ih[grow] + b_hh[grow];

    // out-projection weights (WG0 wave1): lane l covers h indices l + 64*i
    float weff_o[8];
    float be = 0.0f;
#pragma unroll
    for (int i = 0; i < 8; ++i) weff_o[i] = 0.0f;
    if (is_out) {
#pragma unroll
        for (int i = 0; i < 8; ++i) {
            float s = 0.0f;
            for (int p = 0; p < 25; ++p) s += Wout[p] * W1[p * HID + l + 64 * i];
            weff_o[i] = s;
        }
        for (int p = 0; p < 25; ++p) be += b1[p] * Wout[p];
    }
    // pin against in-loop memory clobbers
#pragma unroll
    for (int k = 0; k < KW; ++k) asm volatile("" : "+v"(wr[k]));
#pragma unroll
    for (int k = 0; k < KX; ++k) asm volatile("" : "+v"(wi[k]));
#pragma unroll
    for (int i = 0; i < 8; ++i) asm volatile("" : "+v"(weff_o[i]));
    asm volatile("" : "+v"(brow));
    asm volatile("" : "+v"(be));

    float c = 0.0f;
    float xa[KX];
#pragma unroll
    for (int k = 0; k < KX; ++k) xa[k] = x[j * KX + k];

    bool dead = false;   // safety latch: never hang the device

    for (u32 t = 0; t <= T_SEQ; ++t) {
        if (t == T_SEQ && w != 0) break;   // only WG0 runs the tail iteration

        // ---- x-dot partials for step t (pure VALU; overlaps the poll) ----
        float xd0 = 0.0f, xd1 = 0.0f, xd2 = 0.0f, xd3 = 0.0f;
#pragma unroll
        for (int k = 0; k < KX; k += 4) {
            xd0 += wi[k + 0] * xa[k + 0];
            xd1 += wi[k + 1] * xa[k + 1];
            xd2 += wi[k + 2] * xa[k + 2];
            xd3 += wi[k + 3] * xa[k + 3];
        }
        // xa consumed -> prefetch x_{t+1}. Compute waves: before the barrier
        // (latency hides inside the wait). Poller: after the barrier.
        const int tn = (t + 1 < T_SEQ) ? (int)(t + 1) : (T_SEQ - 1);
        if (wv != 0) {
#pragma unroll
            for (int k = 0; k < KX; k += 4) {
                const float4 x4 = *(const float4*)&x[tn * INP + j * KX + k];
                xa[k + 0] = x4.x; xa[k + 1] = x4.y;
                xa[k + 2] = x4.z; xa[k + 3] = x4.w;
            }
        }

        // ---- wave0 polls 256 packets (4 loads/lane, per-lane early-out) ----
        if (wv == 0 && !dead) {
            const u64* P = hbuf + (t & 1) * NPK;
            float2* HL = (float2*)h_lds[t & 1];
            bool mine = false;
            int guard = 0;
            while (true) {
                if (!mine) {
                    u64 pr[4];
                    bool ok = true;
#pragma unroll
                    for (int i = 0; i < 4; ++i) {
                        pr[i] = __hip_atomic_load(&P[l + 64 * i],
                                                  __ATOMIC_RELAXED,
                                                  __HIP_MEMORY_SCOPE_AGENT);
                        ok = ok && ((((u32)pr[i]) ^ t) & 15u) == 0u;
                    }
                    if (ok) {
#pragma unroll
                        for (int i = 0; i < 4; ++i) {
                            float2 hp;
                            hp.x = __uint_as_float((u32)pr[i]);
                            hp.y = __uint_as_float((u32)(pr[i] >> 32));
                            HL[l + 64 * i] = hp;   // h[2p], h[2p+1]
                        }
                        mine = true;
                    }
                }
                if (__ballot(mine) == ~0ull) break;
                if (++guard > (1 << 22)) { dead = true; break; }  // no hang
            }
        }
        __syncthreads();

        if (t < T_SEQ) {
            float a0 = xd0, a1 = xd1, a2 = xd2, a3 = xd3;
            const float4* hl4 = (const float4*)&h_lds[t & 1][j * KW];
#pragma unroll
            for (int kk = 0; kk < 16; ++kk) {
                const int p = (kk + 2 * j) & 15;
                const float4 h4 = hl4[p];
                a0 += wr[4 * kk + 0] * h4.x;
                a1 += wr[4 * kk + 1] * h4.y;
                a2 += wr[4 * kk + 2] * h4.z;
                a3 += wr[4 * kk + 3] * h4.w;
            }
            // poller's x-prefetch (after barrier, overlaps the h-dot)
            if (wv == 0) {
#pragma unroll
                for (int k = 0; k < KX; k += 4) {
                    const float4 x4 = *(const float4*)&x[tn * INP + j * KX + k];
                    xa[k + 0] = x4.x; xa[k + 1] = x4.y;
                    xa[k + 2] = x4.z; xa[k + 3] = x4.w;
                }
            }
            // xor-butterfly over j: every lane holds its row's full sum
            float acc = (a0 + a1) + (a2 + a3);
            acc += __shfl_xor(acc, 1);
            acc += __shfl_xor(acc, 2);
            acc += __shfl_xor(acc, 4);
            acc += brow;
            // gates of element b live at rw = b, b+2, b+4, b+6 (valid l<16)
            const float ig = acc;
            const float fg = __shfl(acc, l + 16);
            const float gg = __shfl(acc, l + 32);
            const float og = __shfl(acc, l + 48);
            const float iv = fast_sigmoid(ig);
            const float fv = fast_sigmoid(fg);
            const float gv = fast_tanh(gg);
            const float ov = fast_sigmoid(og);
            c = fv * c + iv * gv;
            const float hv = ov * fast_tanh(c);
            // stage this wave's packet (h_even tagged in low nibble, h_odd
            // full) into LDS; publish happens coalesced after the barrier
            const float hv1 = __shfl(hv, 8);     // element b=1 (lane 8)
            if (l == 0) {
                const u32 b0 = (__float_as_uint(hv) & ~15u) | ((t + 1) & 15u);
                const u32 b1v = __float_as_uint(hv1);
                gather_lds[wv] = ((u64)b1v << 32) | (u64)b0;
            }
            __syncthreads();   // barrier B: all 8 packets staged
            // ---- coalesced publish: wave0 lanes 0-7, ONE store instruction
            // (8 contiguous 8B atomic stores -> one 64B fabric transaction)
            if (wv == 0 && l < 8) {
                __hip_atomic_store(&hbuf[((t + 1) & 1) * NPK + w * 8 + l],
                                   gather_lds[l],
                                   __ATOMIC_RELAXED, __HIP_MEMORY_SCOPE_AGENT);
            }
        }

        // out[t-1] = dot(h_{t-1}, w_eff) + b_eff — WG0 wave1, after publish
        if (is_out && t >= 1) {
            float pd = 0.0f;
#pragma unroll
            for (int i = 0; i < 8; ++i)
                pd += h_lds[t & 1][l + 64 * i] * weff_o[i];
            pd += __shfl_xor(pd, 1);
            pd += __shfl_xor(pd, 2);
            pd += __shfl_xor(pd, 4);
            pd += __shfl_xor(pd, 8);
            pd += __shfl_xor(pd, 16);
            pd += __shfl_xor(pd, 32);
            if (l == 0) out[t - 1] = pd + be;
        }
    }
}

extern "C" void kernel_launch(void* const* d_in, const int* in_sizes, int n_in,
                              void* d_out, int out_size, void* d_ws, size_t ws_size,
                              hipStream_t stream)
{
    const float* x    = (const float*)d_in[0];
    const float* W_ih = (const float*)d_in[1];
    const float* W_hh = (const float*)d_in[2];
    const float* b_ih = (const float*)d_in[3];
    const float* b_hh = (const float*)d_in[4];
    const float* W1   = (const float*)d_in[5];
    const float* b1   = (const float*)d_in[6];
    const float* Wout = (const float*)d_in[7];
    float* out = (float*)d_out;

    u64* hbuf = (u64*)d_ws;    // 2 x 256 packets = 4 KB

    // zero packets: tag nibble 0 + h 0 == valid initial state for step 0
    hipMemsetAsync(d_ws, 0, 2 * NPK * sizeof(u64), stream);
    lstm_persist<<<NWG, NTH, 0, stream>>>(x, W_ih, W_hh, b_ih, b_hh, W1, b1,
                                          Wout, hbuf, out);
}